// Round 2
// baseline (204.503 us; speedup 1.0000x reference)
//
#include <hip/hip_runtime.h>
#include <math.h>

#define ALPHA 26
#define ROW_PAD 32      // rn row stride in workspace (128 B, s_load-friendly)
#define TPB 256
#define TILE_FLOATS (TPB * ALPHA)   // 6656 floats = 26624 B -> 6 blocks/CU

typedef __attribute__((address_space(3))) float lds_f;
typedef const __attribute__((address_space(1))) float glb_f;

// Pre-kernel: row-L2-normalize the 26x26 rotor into workspace, rows padded to 32.
__global__ void rotor_norm_kernel(const float* __restrict__ rotor,
                                  float* __restrict__ rn) {
    int i = threadIdx.x;
    if (i < ALPHA) {
        float ss = 0.f;
        #pragma unroll
        for (int j = 0; j < ALPHA; ++j) {
            float v = rotor[i * ALPHA + j];
            ss += v * v;
        }
        float inv = 1.0f / sqrtf(ss);
        #pragma unroll
        for (int j = 0; j < ALPHA; ++j)
            rn[i * ROW_PAD + j] = rotor[i * ALPHA + j] * inv;
    }
}

// out[tok][j] = softmax_j( sum_k x[tok][(k - r) mod 26] * rn[k][j] ),  r = (tok & 8191) % 26
// rn rows are wave-uniform -> scalar loads (SGPR), shared by all 64 lanes.
__global__ __launch_bounds__(TPB) void rotor_main(
        const float* __restrict__ x,
        const float* __restrict__ rn,
        float* __restrict__ out) {
    __shared__ float tile[TILE_FLOATS];

    const int tid = threadIdx.x;
    const int wave = tid >> 6;
    const long long blockTok = (long long)blockIdx.x * TPB;
    const float* gin = x + blockTok * ALPHA;
    float* gout = out + blockTok * ALPHA;

    // ---- Async stage 6656 floats (1664 float4) global -> LDS, unpadded ----
    // LDS dest is wave-uniform base + lane*16 (global_load_lds contract).
    #pragma unroll
    for (int it = 0; it < 6; ++it) {
        int v4 = it * TPB + tid;                               // float4 index
        __builtin_amdgcn_global_load_lds(
            (glb_f*)(gin + v4 * 4),
            (lds_f*)&tile[(it * TPB + wave * 64) * 4],
            16, 0, 0);
    }
    if (tid < 128) {                                           // remainder: 128 float4
        int v4 = 6 * TPB + tid;
        __builtin_amdgcn_global_load_lds(
            (glb_f*)(gin + v4 * 4),
            (lds_f*)&tile[(6 * TPB + wave * 64) * 4],
            16, 0, 0);
    }
    __syncthreads();

    // ---- Gather rotated x into registers: 26 independent ds_read_b32 ----
    const int n = (int)blockTok + tid;     // global token id
    const int r = (n & 8191) % 26;         // S = 8192, position == 1
    int shift = 26 - r; if (shift == 26) shift = 0;   // (0 - r) mod 26

    const float* myx = &tile[tid * ALPHA];   // stride 26: 2-way bank alias = free
    float xv[ALPHA];
    #pragma unroll
    for (int k = 0; k < ALPHA; ++k) {
        int idx = k + shift;
        idx = (idx >= ALPHA) ? idx - ALPHA : idx;
        xv[k] = myx[idx];
    }

    // ---- Fully unrolled 26x26 FMA; rn rows pipeline through SGPRs ----
    float acc[ALPHA];
    #pragma unroll
    for (int j = 0; j < ALPHA; ++j) acc[j] = 0.f;

    #pragma unroll
    for (int k = 0; k < ALPHA; ++k) {
        const float xk = xv[k];
        #pragma unroll
        for (int j = 0; j < ALPHA; ++j)
            acc[j] = fmaf(xk, rn[k * ROW_PAD + j], acc[j]);
    }

    // ---- Softmax over 26 (registers only) ----
    float m = acc[0];
    #pragma unroll
    for (int j = 1; j < ALPHA; ++j) m = fmaxf(m, acc[j]);
    float sum = 0.f;
    #pragma unroll
    for (int j = 0; j < ALPHA; ++j) { acc[j] = __expf(acc[j] - m); sum += acc[j]; }
    float inv = 1.0f / sum;
    #pragma unroll
    for (int j = 0; j < ALPHA; ++j) acc[j] *= inv;

    // ---- Writeback via LDS for coalesced float4 stores ----
    __syncthreads();   // all waves done reading x tile
    #pragma unroll
    for (int j = 0; j < ALPHA; ++j)
        tile[tid * ALPHA + j] = acc[j];    // stride 26: 2-way alias = free
    __syncthreads();

    #pragma unroll
    for (int it = 0; it < 6; ++it) {
        int v4 = it * TPB + tid;
        float4 d = *(const float4*)&tile[v4 * 4];
        *(float4*)(gout + v4 * 4) = d;
    }
    if (tid < 128) {
        int v4 = 6 * TPB + tid;
        float4 d = *(const float4*)&tile[v4 * 4];
        *(float4*)(gout + v4 * 4) = d;
    }
}

extern "C" void kernel_launch(void* const* d_in, const int* in_sizes, int n_in,
                              void* d_out, int out_size, void* d_ws, size_t ws_size,
                              hipStream_t stream) {
    const float* x     = (const float*)d_in[0];   // [128, 8192, 26] fp32
    const float* rotor = (const float*)d_in[1];   // [26, 26] fp32
    float* out = (float*)d_out;                   // [128, 8192, 26] fp32
    float* rn  = (float*)d_ws;                    // 26*32 floats = 3328 B

    rotor_norm_kernel<<<1, 64, 0, stream>>>(rotor, rn);

    const int tokens = out_size / ALPHA;          // 1,048,576
    const int blocks = tokens / TPB;              // 4096
    rotor_main<<<blocks, TPB, 0, stream>>>(x, rn, out);
}

// Round 3
// 202.961 us; speedup vs baseline: 1.0076x; 1.0076x over previous
//
#include <hip/hip_runtime.h>
#include <math.h>

#define ALPHA 26
#define ROW_PAD 32      // rn row stride in workspace (128 B, s_load-friendly)
#define TPB 256

typedef __attribute__((address_space(3))) float lds_f;
typedef const __attribute__((address_space(1))) float glb_f;

// Pre-kernel: row-L2-normalize the 26x26 rotor into workspace, rows padded to 32.
__global__ void rotor_norm_kernel(const float* __restrict__ rotor,
                                  float* __restrict__ rn) {
    int i = threadIdx.x;
    if (i < ALPHA) {
        float ss = 0.f;
        #pragma unroll
        for (int j = 0; j < ALPHA; ++j) {
            float v = rotor[i * ALPHA + j];
            ss += v * v;
        }
        float inv = 1.0f / sqrtf(ss);
        #pragma unroll
        for (int j = 0; j < ALPHA; ++j)
            rn[i * ROW_PAD + j] = rotor[i * ALPHA + j] * inv;
    }
}

// out[tok][j] = softmax_j( sum_k x[tok][(k - r) mod 26] * rn[k][j] ),  r = (tok & 8191) % 26
// BARRIER-FREE: each wave stages/consumes only its own 64-token LDS region.
// rn rows are wave-uniform -> scalar loads (SGPR), shared by all 64 lanes.
__global__ __launch_bounds__(TPB, 6) void rotor_main(
        const float* __restrict__ x,
        const float* __restrict__ rn,
        float* __restrict__ out) {
    __shared__ float tile[TPB * ALPHA];   // 6656 floats = 26624 B -> 6 blocks/CU

    const int tid  = threadIdx.x;
    const int lane = tid & 63;
    const int wave = tid >> 6;

    const long long blockF = (long long)blockIdx.x * (TPB * ALPHA);  // floats
    const int waveF = wave * (64 * ALPHA);                           // 1664 floats
    const float* gin  = x   + blockF;
    float*       gout = out + blockF;

    // ---- Per-wave async staging: 6 x (64 lanes x 16 B) = 1536 floats ----
    #pragma unroll
    for (int it = 0; it < 6; ++it) {
        __builtin_amdgcn_global_load_lds(
            (glb_f*)(gin + waveF + it * 256 + lane * 4),
            (lds_f*)&tile[waveF + it * 256],
            16, 0, 0);
    }
    // Remainder 128 floats via VGPR round-trip (keeps all LDS writes wave-private).
    {
        float2 d = *(const float2*)(gin + waveF + 1536 + lane * 2);
        *(float2*)&tile[waveF + 1536 + lane * 2] = d;
    }
    // Wait for this wave's own staging loads; no block barrier needed.
    asm volatile("s_waitcnt vmcnt(0)" ::: "memory");

    // ---- Gather rotated x into registers: 26 independent ds_read_b32 ----
    const int n = blockIdx.x * TPB + tid;   // global token id
    const int r = (n & 8191) % 26;          // S = 8192, position == 1
    int shift = 26 - r; if (shift == 26) shift = 0;   // (0 - r) mod 26

    const float* myx = &tile[tid * ALPHA];
    float xv[ALPHA];
    #pragma unroll
    for (int k = 0; k < ALPHA; ++k) {
        int idx = k + shift;
        idx = (idx >= ALPHA) ? idx - ALPHA : idx;
        xv[k] = myx[idx];
    }

    // ---- Fully unrolled 26x26 FMA; rn rows pipeline through SGPRs ----
    float acc[ALPHA];
    #pragma unroll
    for (int j = 0; j < ALPHA; ++j) acc[j] = 0.f;

    #pragma unroll
    for (int k = 0; k < ALPHA; ++k) {
        const float xk = xv[k];
        #pragma unroll
        for (int j = 0; j < ALPHA; ++j)
            acc[j] = fmaf(xk, rn[k * ROW_PAD + j], acc[j]);
    }

    // ---- Softmax over 26 (registers only) ----
    float m = acc[0];
    #pragma unroll
    for (int j = 1; j < ALPHA; ++j) m = fmaxf(m, acc[j]);
    float sum = 0.f;
    #pragma unroll
    for (int j = 0; j < ALPHA; ++j) { acc[j] = __expf(acc[j] - m); sum += acc[j]; }
    float inv = 1.0f / sum;
    #pragma unroll
    for (int j = 0; j < ALPHA; ++j) acc[j] *= inv;

    // ---- Writeback through own LDS region (same-wave DS ordering), then
    //      coalesced float4 stores ----
    #pragma unroll
    for (int j = 0; j < ALPHA; ++j)
        tile[tid * ALPHA + j] = acc[j];

    #pragma unroll
    for (int it = 0; it < 6; ++it) {
        float4 d = *(const float4*)&tile[waveF + it * 256 + lane * 4];
        *(float4*)(gout + waveF + it * 256 + lane * 4) = d;
    }
    {
        float2 d = *(const float2*)&tile[waveF + 1536 + lane * 2];
        *(float2*)(gout + waveF + 1536 + lane * 2) = d;
    }
}

extern "C" void kernel_launch(void* const* d_in, const int* in_sizes, int n_in,
                              void* d_out, int out_size, void* d_ws, size_t ws_size,
                              hipStream_t stream) {
    const float* x     = (const float*)d_in[0];   // [128, 8192, 26] fp32
    const float* rotor = (const float*)d_in[1];   // [26, 26] fp32
    float* out = (float*)d_out;                   // [128, 8192, 26] fp32
    float* rn  = (float*)d_ws;                    // 26*32 floats = 3328 B

    rotor_norm_kernel<<<1, 64, 0, stream>>>(rotor, rn);

    const int tokens = out_size / ALPHA;          // 1,048,576
    const int blocks = tokens / TPB;              // 4096
    rotor_main<<<blocks, TPB, 0, stream>>>(x, rn, out);
}

// Round 4
// 194.239 us; speedup vs baseline: 1.0528x; 1.0449x over previous
//
#include <hip/hip_runtime.h>
#include <math.h>

#define ALPHA 26
#define TPB 256
#define ROWF 26                  // stage row stride in floats (token row)
#define WAVEF (64 * ROWF)        // 1664 floats per wave-private region

typedef __attribute__((ext_vector_type(8))) short short8;
typedef __attribute__((ext_vector_type(4))) float float4v;
typedef __attribute__((address_space(3))) float lds_f;
typedef const __attribute__((address_space(1))) float glb_f;

__device__ __forceinline__ unsigned short f2bf(float f) {
    unsigned u = __builtin_bit_cast(unsigned, f);
    u += 0x7FFFu + ((u >> 16) & 1u);          // round-to-nearest-even
    return (unsigned short)(u >> 16);
}

// Pre-kernel: row-L2-normalize rotor, emit bf16 B matrix padded to 32x32 in ws.
// rnb[k][n] = bf16(rotor[k][n]/||rotor[k]||) for k,n<26, else 0.
__global__ void rotor_norm_kernel(const float* __restrict__ rotor,
                                  unsigned short* __restrict__ rnb) {
    int k = threadIdx.x;
    if (k < 32) {
        if (k < ALPHA) {
            float ss = 0.f;
            #pragma unroll
            for (int j = 0; j < ALPHA; ++j) {
                float v = rotor[k * ALPHA + j];
                ss += v * v;
            }
            float inv = 1.0f / sqrtf(ss);
            #pragma unroll
            for (int n = 0; n < 32; ++n)
                rnb[k * 32 + n] = (n < ALPHA) ? f2bf(rotor[k * ALPHA + n] * inv)
                                              : (unsigned short)0;
        } else {
            #pragma unroll
            for (int n = 0; n < 32; ++n) rnb[k * 32 + n] = 0;
        }
    }
}

// out[tok] = softmax( xrot[tok] @ rn ),  xrot[tok][k] = x[tok][(k - r) mod 26],
// r = (tok & 8191) % 26.  GEMM via mfma_f32_16x16x32_bf16: B (= rn) is shared
// by ALL tokens and lives in 8 VGPRs per lane; A-frags gathered rotated from
// the wave-private LDS tile. Barrier-free (wave-private regions only).
__global__ __launch_bounds__(TPB, 6) void rotor_main(
        const float* __restrict__ x,
        const unsigned short* __restrict__ rnb,
        float* __restrict__ out) {
    __shared__ float stage[4 * WAVEF];   // 26624 B -> 6 blocks/CU

    const int tid  = threadIdx.x;
    const int lane = tid & 63;
    const int wave = tid >> 6;
    const int n15  = lane & 15;
    const int quad = lane >> 4;
    const int waveF = wave * WAVEF;

    // ---- B fragments: loaded once, kept in VGPRs for the whole kernel ----
    // B-operand layout (16x16x32): n = lane&15, k = quad*8 + j.
    short8 bfrag0, bfrag1;
    #pragma unroll
    for (int j = 0; j < 8; ++j) {
        int k = quad * 8 + j;
        bfrag0[j] = (short)rnb[k * 32 + n15];
        bfrag1[j] = (short)rnb[k * 32 + 16 + n15];
    }

    const long long blockF = (long long)blockIdx.x * (TPB * ALPHA);
    const float* gin  = x   + blockF;
    float*       gout = out + blockF;

    // ---- Per-wave async staging: 64 tokens x 26 floats ----
    #pragma unroll
    for (int it = 0; it < 6; ++it) {
        __builtin_amdgcn_global_load_lds(
            (glb_f*)(gin + waveF + it * 256 + lane * 4),
            (lds_f*)&stage[waveF + it * 256],
            16, 0, 0);
    }
    {   // 128-float tail via VGPR round trip (keeps LDS writes wave-private)
        float2 d = *(const float2*)(gin + waveF + 1536 + lane * 2);
        *(float2*)&stage[waveF + 1536 + lane * 2] = d;
    }
    asm volatile("s_waitcnt vmcnt(0)" ::: "memory");

    // ---- GEMM: 4 M-tiles x 2 N-tiles of mfma_f32_16x16x32_bf16 ----
    const int tokBase = blockIdx.x * TPB + wave * 64;
    float4v accA[4], accB[4];
    #pragma unroll
    for (int m = 0; m < 4; ++m) {
        accA[m] = (float4v){0.f, 0.f, 0.f, 0.f};
        accB[m] = (float4v){0.f, 0.f, 0.f, 0.f};
    }

    #pragma unroll
    for (int m = 0; m < 4; ++m) {
        // A-operand layout: this lane supplies token m*16 + n15, k = quad*8+j.
        const int tok = tokBase + m * 16 + n15;
        const int r = (tok & 8191) % 26;            // S = 8192, position == 1
        const int rowOff = waveF + (m * 16 + n15) * ROWF;
        const int k0 = quad * 8;
        int idx0 = k0 - r; if (idx0 < 0) idx0 += 26;   // in [0,25]

        short8 af;
        #pragma unroll
        for (int j = 0; j < 8; ++j) {
            int idx = idx0 + j; if (idx >= 26) idx -= 26;   // stays in [0,25]
            float v = stage[rowOff + idx];
            v = (k0 + j < ALPHA) ? v : 0.f;                 // K-pad 26->32
            af[j] = (short)f2bf(v);
        }
        accA[m] = __builtin_amdgcn_mfma_f32_16x16x32_bf16(af, bfrag0, accA[m], 0, 0, 0);
        accB[m] = __builtin_amdgcn_mfma_f32_16x16x32_bf16(af, bfrag1, accB[m], 0, 0, 0);
    }

    // ---- C writeback to wave-private LDS (C/D: col=lane&15, row=quad*4+reg) ----
    #pragma unroll
    for (int m = 0; m < 4; ++m) {
        #pragma unroll
        for (int rg = 0; rg < 4; ++rg) {
            const int base = waveF + (m * 16 + quad * 4 + rg) * ROWF;
            stage[base + n15] = accA[m][rg];
            if (n15 < ALPHA - 16)                     // cols 16..25 only
                stage[base + 16 + n15] = accB[m][rg];
        }
    }
    asm volatile("s_waitcnt lgkmcnt(0)" ::: "memory");

    // ---- Per-lane softmax over own token's 26 logits ----
    const float* myrow = &stage[waveF + lane * ROWF];
    float v[ALPHA];
    #pragma unroll
    for (int j = 0; j < ALPHA; ++j) v[j] = myrow[j];
    float mx = v[0];
    #pragma unroll
    for (int j = 1; j < ALPHA; ++j) mx = fmaxf(mx, v[j]);
    float sum = 0.f;
    #pragma unroll
    for (int j = 0; j < ALPHA; ++j) { v[j] = __expf(v[j] - mx); sum += v[j]; }
    float inv = 1.0f / sum;
    float* wrow = &stage[waveF + lane * ROWF];
    #pragma unroll
    for (int j = 0; j < ALPHA; ++j) wrow[j] = v[j] * inv;

    // ---- Coalesced float4 stores from LDS ----
    #pragma unroll
    for (int it = 0; it < 6; ++it) {
        float4 d = *(const float4*)&stage[waveF + it * 256 + lane * 4];
        *(float4*)(gout + waveF + it * 256 + lane * 4) = d;
    }
    {
        float2 d = *(const float2*)&stage[waveF + 1536 + lane * 2];
        *(float2*)(gout + waveF + 1536 + lane * 2) = d;
    }
}

extern "C" void kernel_launch(void* const* d_in, const int* in_sizes, int n_in,
                              void* d_out, int out_size, void* d_ws, size_t ws_size,
                              hipStream_t stream) {
    const float* x     = (const float*)d_in[0];   // [128, 8192, 26] fp32
    const float* rotor = (const float*)d_in[1];   // [26, 26] fp32
    float* out = (float*)d_out;                   // [128, 8192, 26] fp32
    unsigned short* rnb = (unsigned short*)d_ws;  // bf16 B matrix, 32x32 = 2 KB

    rotor_norm_kernel<<<1, 64, 0, stream>>>(rotor, rnb);

    const int tokens = out_size / ALPHA;          // 1,048,576
    const int blocks = tokens / TPB;              // 4096
    rotor_main<<<blocks, TPB, 0, stream>>>(x, rnb, out);
}